// Round 1
// 295.754 us; speedup vs baseline: 1.0104x; 1.0104x over previous
//
#include <hip/hip_runtime.h>

// Problem constants (from reference)
#define VOCAB 32000
#define D     64
#define B     32
#define S     512
#define NCHUNK 8     // number of time chunks
#define CLEN   64    // chunk length (S / NCHUNK)

typedef float vf4 __attribute__((ext_vector_type(4)));

#define DECAY   0.9f
// 0.9^64, exact double rounded to float: (((0.81^2)^2)^2 ... ) chain
#define DECAY64 0.0011790184577738602f

// ---------------------------------------------------------------------------
// Pass 1: gather content[b,s,:] = emb[x[b,s],:]   (float4 vectorized)
// 1024 blocks x 256 threads. ~8 MB of traffic, ~3 us.
// ---------------------------------------------------------------------------
__global__ void qmn_gather(const int* __restrict__ x,
                           const vf4* __restrict__ emb4,
                           vf4* __restrict__ content4) {
    int tid = blockIdx.x * blockDim.x + threadIdx.x;   // [0, B*S*16)
    int bs  = tid >> 4;
    int d4  = tid & 15;
    int tok = x[bs];
    content4[tid] = emb4[tok * (D / 4) + d4];
}

// ---------------------------------------------------------------------------
// Pass 2: per-chunk partial sums  P[b,c] = sum_{tt<64} 0.9^(63-tt) p_{c*64+tt}
// Linearity of the scan lets all 8 chunks run in PARALLEL (no prescan).
// 1024 blocks (b, c, iBase) x 256 threads (16 i-rows x 16 jq), 64 steps each.
// No state stores -> ~4 us. Output: 4 MiB of partials.
// ---------------------------------------------------------------------------
__global__ __launch_bounds__(256, 4) void qmn_partial(
    const float* __restrict__ content,   // [B, S, D]
    vf4*        __restrict__ P4)         // [B, NCHUNK, D, D/4]
{
    int blk   = blockIdx.x;
    int iBase = (blk & 3) * 16;
    int c     = (blk >> 2) & 7;
    int b     = blk >> 5;

    int jq = threadIdx.x & 15;
    int i  = iBase + (threadIdx.x >> 4);

    const float* cb  = content + (size_t)b * S * D;
    const vf4*   cb4 = (const vf4*)cb;
    const int    t0  = c * CLEN;

    vf4 acc; acc.x = 0.f; acc.y = 0.f; acc.z = 0.f; acc.w = 0.f;

    #pragma unroll 8
    for (int tt = 0; tt < CLEN; ++tt) {
        int t = t0 + tt;
        float ci = cb[t * D + i];
        vf4   cj = cb4[t * (D / 4) + jq];
        acc.x = acc.x * DECAY + ci * cj.x;
        acc.y = acc.y * DECAY + ci * cj.y;
        acc.z = acc.z * DECAY + ci * cj.z;
        acc.w = acc.w * DECAY + ci * cj.w;
    }

    P4[(((b * NCHUNK + c) * D) + i) * (D / 4) + jq] = acc;
}

// ---------------------------------------------------------------------------
// Pass 3: prefix over the 8 chunks.
//   R[b,0]  = I
//   R[b,c]  = 0.9^64 * R[b,c-1] + P[b,c-1]
// One thread per (b, i, jq): 32768 threads = 128 blocks. ~3 us.
// ---------------------------------------------------------------------------
__global__ __launch_bounds__(256) void qmn_prefix(
    const vf4* __restrict__ P4,   // [B, NCHUNK, D, D/4]
    vf4*       __restrict__ R4)   // [B, NCHUNK, D, D/4]
{
    int tid = blockIdx.x * 256 + threadIdx.x;   // [0, B*D*16)
    int jq  = tid & 15;
    int i   = (tid >> 4) & 63;
    int b   = tid >> 10;

    // identity slice
    vf4 r;
    int j0 = jq * 4;
    r.x = (i == j0 + 0) ? 1.0f : 0.0f;
    r.y = (i == j0 + 1) ? 1.0f : 0.0f;
    r.z = (i == j0 + 2) ? 1.0f : 0.0f;
    r.w = (i == j0 + 3) ? 1.0f : 0.0f;

    const vf4* Pb  = P4 + (size_t)b * NCHUNK * D * (D / 4);
    vf4*       Rb  = R4 + (size_t)b * NCHUNK * D * (D / 4);
    const int  off = i * (D / 4) + jq;

    Rb[off] = r;   // c = 0

    #pragma unroll
    for (int c = 1; c < NCHUNK; ++c) {
        vf4 p = Pb[(c - 1) * D * (D / 4) + off];
        r.x = r.x * DECAY64 + p.x;
        r.y = r.y * DECAY64 + p.y;
        r.z = r.z * DECAY64 + p.z;
        r.w = r.w * DECAY64 + p.w;
        Rb[c * D * (D / 4) + off] = r;
    }
}

// ---------------------------------------------------------------------------
// Pass 4: the store kernel. Each block (b, c, iBase) loads its checkpoint
// R[b,c] and immediately streams 64 states with coalesced float4 stores.
// ALL 1024 blocks store from t=0 -> HBM write BW saturated for the whole
// kernel (vs the old staggered-prescan design where only ~1/8 of blocks
// stored at any instant). 256 threads = 16 i-rows x 16 jq; each wave stores
// 1 KiB contiguous per step; a block stores 4 KiB/step.
// ---------------------------------------------------------------------------
__global__ __launch_bounds__(256, 4) void qmn_store(
    const float* __restrict__ content,   // [B, S, D]
    const vf4*  __restrict__ R4,         // [B, NCHUNK, D, D/4]
    vf4*        __restrict__ out4)       // [B, S, D, D] as float4 over j
{
    int blk   = blockIdx.x;
    int iBase = (blk & 3) * 16;
    int c     = (blk >> 2) & 7;
    int b     = blk >> 5;

    int jq = threadIdx.x & 15;
    int i  = iBase + (threadIdx.x >> 4);

    vf4 rho = R4[(((b * NCHUNK + c) * D) + i) * (D / 4) + jq];

    const float* cb  = content + (size_t)b * S * D;
    const vf4*   cb4 = (const vf4*)cb;
    const int tStart = c * CLEN;

    vf4* outp = out4 + (((size_t)(b * S + tStart)) * D + i) * (D / 4) + jq;

    #pragma unroll 8
    for (int tt = 0; tt < CLEN; ++tt) {
        int t = tStart + tt;
        float ci = cb[t * D + i];            // 4 lines/wave, broadcast
        vf4   cj = cb4[t * (D / 4) + jq];    // contiguous 256B row
        rho.x = rho.x * DECAY + ci * cj.x;
        rho.y = rho.y * DECAY + ci * cj.y;
        rho.z = rho.z * DECAY + ci * cj.z;
        rho.w = rho.w * DECAY + ci * cj.w;
        *outp = rho;
        outp += D * (D / 4);                 // next t: +16 KiB
    }
}

// ---------------------------------------------------------------------------
// Launch
// ---------------------------------------------------------------------------
extern "C" void kernel_launch(void* const* d_in, const int* in_sizes, int n_in,
                              void* d_out, int out_size, void* d_ws, size_t ws_size,
                              hipStream_t stream) {
    const int*   x   = (const int*)d_in[0];     // [B, S] token ids
    const float* emb = (const float*)d_in[1];   // [VOCAB, D]
    vf4* out = (vf4*)d_out;                     // [B, S, D, D]

    // workspace layout: content (4 MiB) | P partials (4 MiB) | R checkpoints (4 MiB)
    float* content = (float*)d_ws;
    vf4*   P4      = (vf4*)((char*)d_ws + (size_t)B * S * D * sizeof(float));
    vf4*   R4      = (vf4*)((char*)d_ws + 2 * (size_t)B * S * D * sizeof(float));

    qmn_gather<<<B * S * (D / 4) / 256, 256, 0, stream>>>(
        x, (const vf4*)emb, (vf4*)content);

    qmn_partial<<<B * NCHUNK * 4, 256, 0, stream>>>(content, P4);

    qmn_prefix<<<(B * D * 16) / 256, 256, 0, stream>>>(P4, R4);

    qmn_store<<<B * NCHUNK * 4, 256, 0, stream>>>(content, R4, out);
}